// Round 2
// baseline (717.290 us; speedup 1.0000x reference)
//
#include <hip/hip_runtime.h>

// Problem constants (fixed by setup_inputs: H=W=256, WIN=8, NCAV=2, C=256, HEADS=8)
#define NT   64
#define CDIM 256
#define NHEAD 8
#define SCALE 0.17677669529663687f   // hd^-0.5 = 1/sqrt(32)

typedef short bfrag __attribute__((ext_vector_type(8)));   // 8 bf16 (4 VGPRs)
typedef float f4    __attribute__((ext_vector_type(4)));   // MFMA C/D
typedef unsigned short us4 __attribute__((ext_vector_type(4)));

__device__ __forceinline__ unsigned short f2bf(float f){
  unsigned u = __builtin_bit_cast(unsigned, f);
  u += 0x7FFFu + ((u >> 16) & 1u);       // round-to-nearest-even
  return (unsigned short)(u >> 16);
}
__device__ __forceinline__ unsigned pk2(float a, float b){
  return (unsigned)f2bf(a) | ((unsigned)f2bf(b) << 16);
}
__device__ __forceinline__ f4 mfma16(bfrag a, bfrag b, f4 c){
  return __builtin_amdgcn_mfma_f32_16x16x32_bf16(a, b, c, 0, 0, 0);
}
// lds_x swizzle: 64 rows x 32 16B-units/row; unit ^= row&7 -> 2-way (free)
__device__ __forceinline__ int swx(int row, int u){ return (row << 5) + (u ^ (row & 7)); }

// Convert MFMA C-layout (2 mt-tiles of one 16-token tile: lane holds tok=cc,
// d = mt*16+quad*4+r) to MFMA input-frag layout (lane holds tok=cc, d=quad*8+e).
// d-axis redistribution is quad-local; token stays on cc -> pure in-wave shuffles.
__device__ __forceinline__ bfrag xpose(f4 m0, f4 m1, int quad, int cc){
  int P0m0 = (int)pk2(m0[0], m0[1]);     // d = 0*16 + p*4 + {0,1}
  int P1m0 = (int)pk2(m0[2], m0[3]);     // d = 0*16 + p*4 + {2,3}
  int P0m1 = (int)pk2(m1[0], m1[1]);     // d = 16 + p*4 + {0,1}
  int P1m1 = (int)pk2(m1[2], m1[3]);
  int srcA = ((quad & 1) << 5) + cc;     // lane of quad p = 2*(q&1)
  int srcB = srcA + 16;                  // lane of quad p = 2*(q&1)+1
  int hi = quad >> 1;                    // mt select
  int a0 = __shfl(P0m0, srcA, 64), a1 = __shfl(P0m1, srcA, 64);
  int b0 = __shfl(P1m0, srcA, 64), b1 = __shfl(P1m1, srcA, 64);
  int c0 = __shfl(P0m0, srcB, 64), c1 = __shfl(P0m1, srcB, 64);
  int d0 = __shfl(P1m0, srcB, 64), d1 = __shfl(P1m1, srcB, 64);
  union { bfrag f; int u[4]; } r;
  r.u[0] = hi ? a1 : a0;                 // e = 0,1
  r.u[1] = hi ? b1 : b0;                 // e = 2,3
  r.u[2] = hi ? c1 : c0;                 // e = 4,5
  r.u[3] = hi ? d1 : d0;                 // e = 6,7
  return r.f;
}

// 32ch x 32tok sub-GEMM: A = wt rows [ocb,ocb+32), B = lds_x tokens [tb,tb+32).
// Returns two bias-added input-layout frags (token tiles tb+0..15, tb+16..31).
__device__ __forceinline__ void subgemm32(const unsigned short* __restrict__ wt,
                                          const unsigned short* lx,
                                          const float* __restrict__ bqkv,
                                          int ocb, int tb, int quad, int cc,
                                          bfrag& f0, bfrag& f1)
{
  f4 acc[2][2];
  acc[0][0] = (f4){0,0,0,0}; acc[0][1] = (f4){0,0,0,0};
  acc[1][0] = (f4){0,0,0,0}; acc[1][1] = (f4){0,0,0,0};
  #pragma unroll
  for (int ks = 0; ks < 8; ++ks){
    bfrag a0 = *(const bfrag*)(wt + (ocb +      cc)*256 + ks*32 + quad*8);
    bfrag a1 = *(const bfrag*)(wt + (ocb + 16 + cc)*256 + ks*32 + quad*8);
    bfrag b0 = *(const bfrag*)(&lx[swx(tb +      cc, ks*4 + quad)*8]);
    bfrag b1 = *(const bfrag*)(&lx[swx(tb + 16 + cc, ks*4 + quad)*8]);
    acc[0][0] = mfma16(a0, b0, acc[0][0]);
    acc[0][1] = mfma16(a0, b1, acc[0][1]);
    acc[1][0] = mfma16(a1, b0, acc[1][0]);
    acc[1][1] = mfma16(a1, b1, acc[1][1]);
  }
  #pragma unroll
  for (int mt = 0; mt < 2; ++mt){
    #pragma unroll
    for (int r = 0; r < 4; ++r){
      float bb = bqkv[ocb + mt*16 + quad*4 + r];
      acc[mt][0][r] += bb;
      acc[mt][1][r] += bb;
    }
  }
  f0 = xpose(acc[0][0], acc[1][0], quad, cc);
  f1 = xpose(acc[0][1], acc[1][1], quad, cc);
}

// ---------------------------------------------------------------------------
// Prep: build bf16 W^T (q-scaled), fused bias vector, rel_bias table, ego bias
// ---------------------------------------------------------------------------
__global__ void prep_kernel(const float* __restrict__ aff,
                            const float* __restrict__ Wq,  const float* __restrict__ bq,
                            const float* __restrict__ Wkv, const float* __restrict__ bkv,
                            const float* __restrict__ Wp,
                            const float* __restrict__ relt, const float* __restrict__ egot,
                            unsigned short* __restrict__ wt, float* __restrict__ relb,
                            float* __restrict__ egob, float* __restrict__ bqkv)
{
  const int bid = blockIdx.x, tid = threadIdx.x;
  if (bid < 256) {                        // tiled weight transpose + bf16
    __shared__ float t[32][33];
    const int r0 = (bid >> 3) * 32;       // out_ch tile (1024/32)
    const int c0 = (bid & 7) * 32;        // in_ch tile  (256/32)
    const int rl = tid & 31, ch = tid >> 5;
    for (int k = 0; k < 4; ++k){          // coalesced source reads (r contiguous)
      int c = c0 + ch + k*8, r = r0 + rl;
      float v;
      if (r < 256)      v = Wq[c*256 + r] * SCALE;
      else if (r < 768) v = Wkv[c*512 + (r - 256)];   // k: 0..255, v: 256..511
      else              v = Wp[c*256 + (r - 768)];
      t[rl][ch + k*8] = v;
    }
    __syncthreads();
    for (int k = 0; k < 4; ++k){          // coalesced dest writes (c contiguous)
      int orr = ch + k*8;
      wt[(r0 + orr)*256 + c0 + rl] = f2bf(t[orr][rl]);
    }
  } else if (bid < 384) {                 // rel_bias: e = h*4096 + i*64 + j
    int e = (bid - 256)*256 + tid;
    int h = e >> 12, i = (e >> 6) & 63, j = e & 63;
    int yi = i >> 3, xi = i & 7, yj = j >> 3, xj = j & 7;
    int ridx = (yi - yj + 7)*15 + (xi - xj + 7);
    relb[e] = relt[ridx*8 + h];
  } else if (bid == 384) {                // ego bias (global max-reduce inside)
    __shared__ float red[256];
    float ex[2], ey[2];
    for (int cv = 0; cv < 2; ++cv){
      const float* A = aff + cv*6;
      ex[cv] = (A[0] + A[1])*128.0f + A[2];
      ey[cv] = (A[3] + A[4])*128.0f + A[5];
    }
    float dl = 0.0f;
    for (int p = 0; p < 4; ++p){
      int t2 = p*256 + tid;
      float cx = (float)((t2 & 31)*8 + 4), cy = (float)((t2 >> 5)*8 + 4);
      for (int cv = 0; cv < 2; ++cv){
        float dx = cx - ex[cv], dy = cy - ey[cv];
        dl = fmaxf(dl, sqrtf(dx*dx + dy*dy));
      }
    }
    red[tid] = dl; __syncthreads();
    for (int s = 128; s > 0; s >>= 1){
      if (tid < s) red[tid] = fmaxf(red[tid], red[tid + s]);
      __syncthreads();
    }
    float dmax = red[0] + 1e-6f;
    const float PI_F = 3.14159265358979f;
    for (int p = 0; p < 4; ++p){
      int t2 = p*256 + tid;
      float cx = (float)((t2 & 31)*8 + 4), cy = (float)((t2 >> 5)*8 + 4);
      for (int cv = 0; cv < 2; ++cv){
        float dx = cx - ex[cv], dy = cy - ey[cv];
        float d = sqrtf(dx*dx + dy*dy);
        float ang = atan2f(dy, dx);
        int db = (int)(d / dmax * 3.0f);
        int ab = (int)((ang + PI_F) / (2.0f*PI_F) * 3.0f);
        int idx = db*4 + ab;
        int bw = cv*1024 + t2;
        for (int h2 = 0; h2 < 8; ++h2)
          egob[bw*8 + h2] = egot[idx*8 + h2];
      }
    }
  } else {                                // fused qkv bias (q part scaled)
    for (int j = tid; j < 768; j += 256)
      bqkv[j] = (j < 256) ? bq[j]*SCALE : bkv[j - 256];
  }
}

// ---------------------------------------------------------------------------
// Fused window attention: one block per window, 1024 threads (16 waves).
// LDS = 64 KiB -> 2 blocks/CU (8 waves/SIMD): q,k never touch LDS (in-register
// via xpose shuffles; k computed by both halves of a head); only v round-trips.
//   lds_x: 32 KiB (x bf16 swizzled -> P scratch -> y bf16)
//   lds_v: 32 KiB (vT per head 32x64, unit-swizzled)
// ---------------------------------------------------------------------------
__global__ __launch_bounds__(1024, 8) void attn_kernel(
    const float* __restrict__ x, const float* __restrict__ wvec,
    const float* __restrict__ bp, float* __restrict__ out,
    const unsigned short* __restrict__ wt, const float* __restrict__ relb,
    const float* __restrict__ egob, const float* __restrict__ bqkv)
{
  __shared__ unsigned short lds_x[NT*CDIM];      // 32 KiB
  __shared__ unsigned short lds_v[NHEAD*2048];   // 32 KiB

  const int b = blockIdx.x;
  const int tid = threadIdx.x;
  const int wv = tid >> 6, lane = tid & 63;
  const int quad = lane >> 4, cc = lane & 15;
  const int h = wv >> 1, half = wv & 1;

  // ---- stage x window -> bf16 LDS (swizzled) ----
  const float4* xg = (const float4*)(x + (size_t)b*(NT*CDIM));
  for (int it = 0; it < 4; ++it){
    int i4 = tid + it*1024;
    float4 v = xg[i4];
    us4 pk = { f2bf(v.x), f2bf(v.y), f2bf(v.z), f2bf(v.w) };
    int row = i4 >> 6, u = (i4 & 63) >> 1, hf = i4 & 1;
    *(us4*)(&lds_x[swx(row, u)*8 + hf*4]) = pk;
  }
  float w0 = wvec[0], w1 = wvec[1];
  float wm = fmaxf(w0, w1);
  float e0 = __expf(w0 - wm), e1 = __expf(w1 - wm);
  float ws0 = e0/(e0+e1), ws1 = e1/(e0+e1);
  __syncthreads();

  // ---- phase 1: per-wave qkv for (head h, token-half). ----
  // V sub-GEMM first (acc freed earliest) -> LDS vT
  {
    f4 acc[2][2];
    acc[0][0] = (f4){0,0,0,0}; acc[0][1] = (f4){0,0,0,0};
    acc[1][0] = (f4){0,0,0,0}; acc[1][1] = (f4){0,0,0,0};
    const int ocb = 512 + h*32;
    const int tb = half*32;
    #pragma unroll
    for (int ks = 0; ks < 8; ++ks){
      bfrag a0 = *(const bfrag*)(wt + (ocb +      cc)*256 + ks*32 + quad*8);
      bfrag a1 = *(const bfrag*)(wt + (ocb + 16 + cc)*256 + ks*32 + quad*8);
      bfrag b0 = *(const bfrag*)(&lds_x[swx(tb +      cc, ks*4 + quad)*8]);
      bfrag b1 = *(const bfrag*)(&lds_x[swx(tb + 16 + cc, ks*4 + quad)*8]);
      acc[0][0] = mfma16(a0, b0, acc[0][0]);
      acc[0][1] = mfma16(a0, b1, acc[0][1]);
      acc[1][0] = mfma16(a1, b0, acc[1][0]);
      acc[1][1] = mfma16(a1, b1, acc[1][1]);
    }
    unsigned short* vs = &lds_v[h*2048];
    #pragma unroll
    for (int mt = 0; mt < 2; ++mt){
      #pragma unroll
      for (int ntl = 0; ntl < 2; ++ntl){
        int tok = tb + ntl*16 + cc;
        int tu = tok >> 3, te = tok & 7;
        #pragma unroll
        for (int r = 0; r < 4; ++r){
          int d = mt*16 + quad*4 + r;
          vs[d*64 + ((tu ^ (d & 7)) << 3) + te] = f2bf(acc[mt][ntl][r] + bqkv[ocb + d]);
        }
      }
    }
  }
  // Q (own half's tokens) -> registers
  bfrag aq0, aq1;
  subgemm32(wt, lds_x, bqkv, h*32, half*32, quad, cc, aq0, aq1);
  // K (all 64 tokens, 2 passes interleaved with S-MFMA to shorten live ranges)
  f4 S[2][4];
  {
    bfrag bk0, bk1;
    subgemm32(wt, lds_x, bqkv, 256 + h*32, 0, quad, cc, bk0, bk1);
    f4 z = (f4){0,0,0,0};
    S[0][0] = mfma16(aq0, bk0, z);
    S[0][1] = mfma16(aq0, bk1, z);
    S[1][0] = mfma16(aq1, bk0, z);
    S[1][1] = mfma16(aq1, bk1, z);
  }
  {
    bfrag bk2, bk3;
    subgemm32(wt, lds_x, bqkv, 256 + h*32, 32, quad, cc, bk2, bk3);
    f4 z = (f4){0,0,0,0};
    S[0][2] = mfma16(aq0, bk2, z);
    S[0][3] = mfma16(aq0, bk3, z);
    S[1][2] = mfma16(aq1, bk2, z);
    S[1][3] = mfma16(aq1, bk3, z);
  }

  // ---- phase 2: logits + biases + softmax stats (register-only) ----
  f4 yacc[2][2];
  {
    float ego = egob[b*8 + h];
    const float* rb = relb + h*4096;
    float a[2][4][4];                        // [it][r][jt]
    #pragma unroll
    for (int it = 0; it < 2; ++it)
      #pragma unroll
      for (int jt = 0; jt < 4; ++jt){
        int jj = jt*16 + cc;
        #pragma unroll
        for (int r = 0; r < 4; ++r){
          int ii = half*32 + it*16 + quad*4 + r;
          a[it][r][jt] = S[it][jt][r] + rb[ii*64 + jj] + ego;
        }
      }
    float rmax[2][4], rinv[2][4];
    #pragma unroll
    for (int it = 0; it < 2; ++it)
      #pragma unroll
      for (int r = 0; r < 4; ++r){
        float m = fmaxf(fmaxf(a[it][r][0], a[it][r][1]), fmaxf(a[it][r][2], a[it][r][3]));
        for (int off = 1; off < 16; off <<= 1) m = fmaxf(m, __shfl_xor(m, off, 64));
        float s = 0.0f;
        #pragma unroll
        for (int jt = 0; jt < 4; ++jt) s += __expf(a[it][r][jt] - m);
        for (int off = 1; off < 16; off <<= 1) s += __shfl_xor(s, off, 64);
        rmax[it][r] = m; rinv[it][r] = 1.0f / s;
      }

    __syncthreads();   // all lds_x reads + lds_v writes done block-wide

    // blended P (C-layout) -> wave-private swizzled LDS chunk -> A-layout -> PV
    #pragma unroll
    for (int it = 0; it < 2; ++it)
      #pragma unroll
      for (int nt = 0; nt < 2; ++nt) yacc[it][nt] = (f4){0,0,0,0};
    unsigned short* Pw = &lds_x[wv*1024];    // 32 rows x 32 cols, unit ^= row&3
    const unsigned short* vts = &lds_v[h*2048];
    for (int chunk = 0; chunk < 2; ++chunk){
      #pragma unroll
      for (int it = 0; it < 2; ++it)
        #pragma unroll
        for (int jtl = 0; jtl < 2; ++jtl){
          int jt = chunk*2 + jtl;
          #pragma unroll
          for (int r = 0; r < 4; ++r){
            float av = a[it][r][jt];
            float rl = fmaxf(av, 0.0f);
            float p = ws0 * __expf(av - rmax[it][r]) * rinv[it][r] + ws1 * rl * rl;
            int row = it*16 + quad*4 + r, col = jtl*16 + cc;
            Pw[row*32 + (((col>>3) ^ (row&3))<<3) + (col&7)] = f2bf(p);
          }
        }
      bfrag pa[2], pb[2];
      #pragma unroll
      for (int itl = 0; itl < 2; ++itl){
        int row = itl*16 + cc;
        pa[itl] = *(const bfrag*)(&Pw[row*32 + ((quad ^ (row&3))<<3)]);
      }
      #pragma unroll
      for (int nt = 0; nt < 2; ++nt){
        int row = nt*16 + cc;
        pb[nt] = *(const bfrag*)(&vts[row*64 + (((chunk*4 + quad) ^ (row&7))<<3)]);
      }
      #pragma unroll
      for (int itl = 0; itl < 2; ++itl)
        #pragma unroll
        for (int nt = 0; nt < 2; ++nt)
          yacc[itl][nt] = mfma16(pa[itl], pb[nt], yacc[itl][nt]);
    }
  }
  __syncthreads();                           // all P reads done before y overwrites lds_x
  // y (64x256 bf16, token-major, swizzled) into lds_x
  #pragma unroll
  for (int itl = 0; itl < 2; ++itl)
    #pragma unroll
    for (int nt = 0; nt < 2; ++nt)
      #pragma unroll
      for (int r = 0; r < 4; ++r){
        int ii = half*32 + itl*16 + quad*4 + r;
        int col = h*32 + nt*16 + cc;
        lds_x[swx(ii, col>>3)*8 + (col&7)] = f2bf(yacc[itl][nt][r]);
      }
  __syncthreads();

  // ---- phase 3: out = y @ Wp + bp ----
  {
    const int mt = wv & 3;                   // token tile
    const int cb = (wv >> 2)*64;             // 4 col tiles
    f4 o[4];
    #pragma unroll
    for (int nt = 0; nt < 4; ++nt) o[nt] = (f4){0,0,0,0};
    #pragma unroll
    for (int ks = 0; ks < 8; ++ks){
      bfrag ay = *(const bfrag*)(&lds_x[swx(mt*16 + cc, ks*4 + quad)*8]);
      #pragma unroll
      for (int nt = 0; nt < 4; ++nt){
        bfrag bw = *(const bfrag*)(wt + (768 + cb + nt*16 + cc)*256 + ks*32 + quad*8);
        o[nt] = mfma16(ay, bw, o[nt]);
      }
    }
    float* og = out + (size_t)b*(NT*CDIM);
    #pragma unroll
    for (int nt = 0; nt < 4; ++nt){
      int col = cb + nt*16 + cc;
      float bpv = bp[col];
      #pragma unroll
      for (int r = 0; r < 4; ++r){
        int tok = mt*16 + quad*4 + r;
        og[tok*256 + col] = o[nt][r] + bpv;
      }
    }
  }
}

extern "C" void kernel_launch(void* const* d_in, const int* in_sizes, int n_in,
                              void* d_out, int out_size, void* d_ws, size_t ws_size,
                              hipStream_t stream)
{
  const float* x    = (const float*)d_in[0];
  const float* aff  = (const float*)d_in[1];
  const float* Wq   = (const float*)d_in[2];
  const float* bq   = (const float*)d_in[3];
  const float* Wkv  = (const float*)d_in[4];
  const float* bkv  = (const float*)d_in[5];
  const float* Wp   = (const float*)d_in[6];
  const float* bp   = (const float*)d_in[7];
  const float* relt = (const float*)d_in[8];
  const float* egot = (const float*)d_in[9];
  const float* w    = (const float*)d_in[10];
  float* out = (float*)d_out;

  char* ws = (char*)d_ws;
  unsigned short* wt = (unsigned short*)ws;       // 512 KiB bf16 W^T
  float* relb = (float*)(ws + 524288);            // 128 KiB
  float* egob = (float*)(ws + 655360);            //  64 KiB
  float* bqkv = (float*)(ws + 720896);            //   3 KiB

  hipLaunchKernelGGL(prep_kernel, dim3(386), dim3(256), 0, stream,
                     aff, Wq, bq, Wkv, bkv, Wp, relt, egot, wt, relb, egob, bqkv);
  hipLaunchKernelGGL(attn_kernel, dim3(2048), dim3(1024), 0, stream,
                     x, w, bp, out, wt, relb, egob, bqkv);
}

// Round 4
// 659.221 us; speedup vs baseline: 1.0881x; 1.0881x over previous
//
#include <hip/hip_runtime.h>

// Problem constants (fixed by setup_inputs: H=W=256, WIN=8, NCAV=2, C=256, HEADS=8)
#define NT   64
#define CDIM 256
#define NHEAD 8
#define SCALE 0.17677669529663687f   // hd^-0.5 = 1/sqrt(32)

typedef short bfrag __attribute__((ext_vector_type(8)));   // 8 bf16 (4 VGPRs)
typedef float f4    __attribute__((ext_vector_type(4)));   // MFMA C/D
typedef unsigned short us4 __attribute__((ext_vector_type(4)));

__device__ __forceinline__ unsigned short f2bf(float f){
  unsigned u = __builtin_bit_cast(unsigned, f);
  u += 0x7FFFu + ((u >> 16) & 1u);       // round-to-nearest-even
  return (unsigned short)(u >> 16);
}
__device__ __forceinline__ unsigned pk2(float a, float b){
  return (unsigned)f2bf(a) | ((unsigned)f2bf(b) << 16);
}
__device__ __forceinline__ f4 mfma16(bfrag a, bfrag b, f4 c){
  return __builtin_amdgcn_mfma_f32_16x16x32_bf16(a, b, c, 0, 0, 0);
}
// swizzle: 64 rows x 32 16B-units/row; unit ^= row&7 -> 2-way (free)
__device__ __forceinline__ int swx(int row, int u){ return (row << 5) + (u ^ (row & 7)); }

// Convert MFMA C-layout (2 mt-tiles of one 16-token tile: lane holds tok=cc,
// d = mt*16+quad*4+r) to MFMA input-frag layout (lane holds tok=cc, d=quad*8+e).
// d-axis redistribution is quad-local; token stays on cc -> pure in-wave shuffles.
__device__ __forceinline__ bfrag xpose(f4 m0, f4 m1, int quad, int cc){
  int P0m0 = (int)pk2(m0[0], m0[1]);
  int P1m0 = (int)pk2(m0[2], m0[3]);
  int P0m1 = (int)pk2(m1[0], m1[1]);
  int P1m1 = (int)pk2(m1[2], m1[3]);
  int srcA = ((quad & 1) << 5) + cc;
  int srcB = srcA + 16;
  int hi = quad >> 1;
  int a0 = __shfl(P0m0, srcA, 64), a1 = __shfl(P0m1, srcA, 64);
  int b0 = __shfl(P1m0, srcA, 64), b1 = __shfl(P1m1, srcA, 64);
  int c0 = __shfl(P0m0, srcB, 64), c1 = __shfl(P0m1, srcB, 64);
  int d0 = __shfl(P1m0, srcB, 64), d1 = __shfl(P1m1, srcB, 64);
  union { bfrag f; int u[4]; } r;
  r.u[0] = hi ? a1 : a0;
  r.u[1] = hi ? b1 : b0;
  r.u[2] = hi ? c1 : c0;
  r.u[3] = hi ? d1 : d0;
  return r.f;
}

// 32ch x 32tok sub-GEMM: A = wt rows [ocb,ocb+32), B = x tokens [tb,tb+32) from LDS.
// Returns two bias-added input-layout frags (token tiles tb+0..15, tb+16..31).
__device__ __forceinline__ void subgemm32(const unsigned short* __restrict__ wt,
                                          const unsigned short* lx,
                                          const float* __restrict__ bqkv,
                                          int ocb, int tb, int quad, int cc,
                                          bfrag& f0, bfrag& f1)
{
  f4 acc[2][2];
  acc[0][0] = (f4){0,0,0,0}; acc[0][1] = (f4){0,0,0,0};
  acc[1][0] = (f4){0,0,0,0}; acc[1][1] = (f4){0,0,0,0};
  #pragma unroll
  for (int ks = 0; ks < 8; ++ks){
    bfrag a0 = *(const bfrag*)(wt + (ocb +      cc)*256 + ks*32 + quad*8);
    bfrag a1 = *(const bfrag*)(wt + (ocb + 16 + cc)*256 + ks*32 + quad*8);
    bfrag b0 = *(const bfrag*)(&lx[swx(tb +      cc, ks*4 + quad)*8]);
    bfrag b1 = *(const bfrag*)(&lx[swx(tb + 16 + cc, ks*4 + quad)*8]);
    acc[0][0] = mfma16(a0, b0, acc[0][0]);
    acc[0][1] = mfma16(a0, b1, acc[0][1]);
    acc[1][0] = mfma16(a1, b0, acc[1][0]);
    acc[1][1] = mfma16(a1, b1, acc[1][1]);
  }
  #pragma unroll
  for (int mt = 0; mt < 2; ++mt)
    #pragma unroll
    for (int r = 0; r < 4; ++r){
      float bb = bqkv[ocb + mt*16 + quad*4 + r];
      acc[mt][0][r] += bb;
      acc[mt][1][r] += bb;
    }
  f0 = xpose(acc[0][0], acc[1][0], quad, cc);
  f1 = xpose(acc[0][1], acc[1][1], quad, cc);
}

// ---------------------------------------------------------------------------
// Prep: build bf16 W^T (q-scaled), fused bias vector, rel_bias table, ego bias
// ---------------------------------------------------------------------------
__global__ void prep_kernel(const float* __restrict__ aff,
                            const float* __restrict__ Wq,  const float* __restrict__ bq,
                            const float* __restrict__ Wkv, const float* __restrict__ bkv,
                            const float* __restrict__ Wp,
                            const float* __restrict__ relt, const float* __restrict__ egot,
                            unsigned short* __restrict__ wt, float* __restrict__ relb,
                            float* __restrict__ egob, float* __restrict__ bqkv)
{
  const int bid = blockIdx.x, tid = threadIdx.x;
  if (bid < 256) {                        // tiled weight transpose + bf16
    __shared__ float t[32][33];
    const int r0 = (bid >> 3) * 32;
    const int c0 = (bid & 7) * 32;
    const int rl = tid & 31, ch = tid >> 5;
    for (int k = 0; k < 4; ++k){
      int c = c0 + ch + k*8, r = r0 + rl;
      float v;
      if (r < 256)      v = Wq[c*256 + r] * SCALE;
      else if (r < 768) v = Wkv[c*512 + (r - 256)];
      else              v = Wp[c*256 + (r - 768)];
      t[rl][ch + k*8] = v;
    }
    __syncthreads();
    for (int k = 0; k < 4; ++k){
      int orr = ch + k*8;
      wt[(r0 + orr)*256 + c0 + rl] = f2bf(t[orr][rl]);
    }
  } else if (bid < 384) {                 // rel_bias: e = h*4096 + i*64 + j
    int e = (bid - 256)*256 + tid;
    int h = e >> 12, i = (e >> 6) & 63, j = e & 63;
    int yi = i >> 3, xi = i & 7, yj = j >> 3, xj = j & 7;
    int ridx = (yi - yj + 7)*15 + (xi - xj + 7);
    relb[e] = relt[ridx*8 + h];
  } else if (bid == 384) {                // ego bias (global max-reduce inside)
    __shared__ float red[256];
    float ex[2], ey[2];
    for (int cv = 0; cv < 2; ++cv){
      const float* A = aff + cv*6;
      ex[cv] = (A[0] + A[1])*128.0f + A[2];
      ey[cv] = (A[3] + A[4])*128.0f + A[5];
    }
    float dl = 0.0f;
    for (int p = 0; p < 4; ++p){
      int t2 = p*256 + tid;
      float cx = (float)((t2 & 31)*8 + 4), cy = (float)((t2 >> 5)*8 + 4);
      for (int cv = 0; cv < 2; ++cv){
        float dx = cx - ex[cv], dy = cy - ey[cv];
        dl = fmaxf(dl, sqrtf(dx*dx + dy*dy));
      }
    }
    red[tid] = dl; __syncthreads();
    for (int s = 128; s > 0; s >>= 1){
      if (tid < s) red[tid] = fmaxf(red[tid], red[tid + s]);
      __syncthreads();
    }
    float dmax = red[0] + 1e-6f;
    const float PI_F = 3.14159265358979f;
    for (int p = 0; p < 4; ++p){
      int t2 = p*256 + tid;
      float cx = (float)((t2 & 31)*8 + 4), cy = (float)((t2 >> 5)*8 + 4);
      for (int cv = 0; cv < 2; ++cv){
        float dx = cx - ex[cv], dy = cy - ey[cv];
        float d = sqrtf(dx*dx + dy*dy);
        float ang = atan2f(dy, dx);
        int db = (int)(d / dmax * 3.0f);
        int ab = (int)((ang + PI_F) / (2.0f*PI_F) * 3.0f);
        int idx = db*4 + ab;
        int bw = cv*1024 + t2;
        for (int h2 = 0; h2 < 8; ++h2)
          egob[bw*8 + h2] = egot[idx*8 + h2];
      }
    }
  } else {                                // fused qkv bias (q part scaled)
    for (int j = tid; j < 768; j += 256)
      bqkv[j] = (j < 256) ? bq[j]*SCALE : bkv[j - 256];
  }
}

// ---------------------------------------------------------------------------
// Fused window attention: one block per window, 1024 threads (16 waves).
// LDS = 64 KiB -> 2 blocks/CU (8 waves/SIMD). Regions are time-multiplexed:
//   ldsA (32 KiB): x bf16 swizzled  -> vT per head (32x64 swizzled)
//   ldsB (32 KiB): k frags (lane-indexed) -> P scratch -> y bf16 swizzled
// q in registers (subgemm+xpose); k computed once per half, shared via ldsB.
// ---------------------------------------------------------------------------
__global__ __launch_bounds__(1024, 8) void attn_kernel(
    const float* __restrict__ x, const float* __restrict__ wvec,
    const float* __restrict__ bp, float* __restrict__ out,
    const unsigned short* __restrict__ wt, const float* __restrict__ relb,
    const float* __restrict__ egob, const float* __restrict__ bqkv)
{
  __shared__ unsigned short ldsA[NT*CDIM];       // 32 KiB (16384 shorts)
  __shared__ unsigned short ldsB[NT*CDIM];       // 32 KiB (16384 shorts)

  const int b = blockIdx.x;
  const int tid = threadIdx.x;
  const int wv = tid >> 6, lane = tid & 63;
  const int quad = lane >> 4, cc = lane & 15;
  const int h = wv >> 1, half = wv & 1;

  // ---- stage x window -> bf16 ldsA (swizzled) ----
  const float4* xg = (const float4*)(x + (size_t)b*(NT*CDIM));
  for (int it = 0; it < 4; ++it){
    int i4 = tid + it*1024;
    float4 v = xg[i4];
    us4 pk = { f2bf(v.x), f2bf(v.y), f2bf(v.z), f2bf(v.w) };
    int row = i4 >> 6, u = (i4 & 63) >> 1, hf = i4 & 1;
    *(us4*)(&ldsA[swx(row, u)*8 + hf*4]) = pk;
  }
  float w0 = wvec[0], w1 = wvec[1];
  float wm = fmaxf(w0, w1);
  float e0 = __expf(w0 - wm), e1 = __expf(w1 - wm);
  float ws0 = e0/(e0+e1), ws1 = e1/(e0+e1);
  __syncthreads();                               // b0: x staged

  // ---- phase 1: per-wave (head h, token-half) q,k,v ----
  bfrag aq0, aq1;
  subgemm32(wt, ldsA, bqkv, h*32, half*32, quad, cc, aq0, aq1);          // q -> regs
  {
    bfrag kf0, kf1;                                                       // k -> ldsB
    subgemm32(wt, ldsA, bqkv, 256 + h*32, half*32, quad, cc, kf0, kf1);
    *(bfrag*)(&ldsB[h*2048 + (half*2 + 0)*512 + lane*8]) = kf0;
    *(bfrag*)(&ldsB[h*2048 + (half*2 + 1)*512 + lane*8]) = kf1;
  }
  f4 vacc[2][2];                                                          // v -> regs (C-layout)
  {
    vacc[0][0] = (f4){0,0,0,0}; vacc[0][1] = (f4){0,0,0,0};
    vacc[1][0] = (f4){0,0,0,0}; vacc[1][1] = (f4){0,0,0,0};
    const int ocb = 512 + h*32, tb = half*32;
    #pragma unroll
    for (int ks = 0; ks < 8; ++ks){
      bfrag a0 = *(const bfrag*)(wt + (ocb +      cc)*256 + ks*32 + quad*8);
      bfrag a1 = *(const bfrag*)(wt + (ocb + 16 + cc)*256 + ks*32 + quad*8);
      bfrag b0 = *(const bfrag*)(&ldsA[swx(tb +      cc, ks*4 + quad)*8]);
      bfrag b1 = *(const bfrag*)(&ldsA[swx(tb + 16 + cc, ks*4 + quad)*8]);
      vacc[0][0] = mfma16(a0, b0, vacc[0][0]);
      vacc[0][1] = mfma16(a0, b1, vacc[0][1]);
      vacc[1][0] = mfma16(a1, b0, vacc[1][0]);
      vacc[1][1] = mfma16(a1, b1, vacc[1][1]);
    }
  }
  __syncthreads();                               // b1: x reads + k writes done

  // ---- vT (bias-added) into former x region (ldsA), swizzled [d][tok] ----
  {
    unsigned short* vs = &ldsA[h*2048];
    #pragma unroll
    for (int mt = 0; mt < 2; ++mt)
      #pragma unroll
      for (int ntl = 0; ntl < 2; ++ntl){
        int tok = half*32 + ntl*16 + cc;
        int tu = tok >> 3, te = tok & 7;
        #pragma unroll
        for (int r = 0; r < 4; ++r){
          int d = mt*16 + quad*4 + r;
          vs[d*64 + ((tu ^ (d & 7)) << 3) + te] =
              f2bf(vacc[mt][ntl][r] + bqkv[512 + h*32 + d]);
        }
      }
  }

  // ---- QK^T from register q and LDS k-frags ----
  f4 S[2][4];
  #pragma unroll
  for (int jt = 0; jt < 4; ++jt){
    bfrag bk = *(const bfrag*)(&ldsB[h*2048 + jt*512 + lane*8]);
    f4 z = (f4){0,0,0,0};
    S[0][jt] = mfma16(aq0, bk, z);
    S[1][jt] = mfma16(aq1, bk, z);
  }

  // ---- logits + biases + softmax stats (Z = m + log(sum)) ----
  f4 yacc[2][2];
  {
    float ego = egob[b*8 + h];
    const float* rb = relb + h*4096;
    float a[2][4][4];                        // [it][r][jt]
    #pragma unroll
    for (int it = 0; it < 2; ++it)
      #pragma unroll
      for (int jt = 0; jt < 4; ++jt){
        int jj = jt*16 + cc;
        #pragma unroll
        for (int r = 0; r < 4; ++r){
          int ii = half*32 + it*16 + quad*4 + r;
          a[it][r][jt] = S[it][jt][r] + rb[ii*64 + jj] + ego;
        }
      }
    float Z[2][4];
    #pragma unroll
    for (int it = 0; it < 2; ++it)
      #pragma unroll
      for (int r = 0; r < 4; ++r){
        float m = fmaxf(fmaxf(a[it][r][0], a[it][r][1]), fmaxf(a[it][r][2], a[it][r][3]));
        for (int off = 1; off < 16; off <<= 1) m = fmaxf(m, __shfl_xor(m, off, 64));
        float s = 0.0f;
        #pragma unroll
        for (int jt = 0; jt < 4; ++jt) s += __expf(a[it][r][jt] - m);
        for (int off = 1; off < 16; off <<= 1) s += __shfl_xor(s, off, 64);
        Z[it][r] = m + __logf(s);
      }

    __syncthreads();                           // b2: k reads + vT writes done

    // blended P (C-layout) -> wave-private swizzled chunk in ldsB -> PV
    #pragma unroll
    for (int it = 0; it < 2; ++it)
      #pragma unroll
      for (int nt = 0; nt < 2; ++nt) yacc[it][nt] = (f4){0,0,0,0};
    unsigned short* Pw = &ldsB[wv*1024];       // 32 rows x 32 cols, unit ^= row&3
    const unsigned short* vts = &ldsA[h*2048];
    for (int chunk = 0; chunk < 2; ++chunk){
      #pragma unroll
      for (int it = 0; it < 2; ++it)
        #pragma unroll
        for (int jtl = 0; jtl < 2; ++jtl){
          int jt = chunk*2 + jtl;
          #pragma unroll
          for (int r = 0; r < 4; ++r){
            float av = a[it][r][jt];
            float rl = fmaxf(av, 0.0f);
            float p = ws0 * __expf(av - Z[it][r]) + ws1 * rl * rl;
            int row = it*16 + quad*4 + r, col = jtl*16 + cc;
            Pw[row*32 + (((col>>3) ^ (row&3))<<3) + (col&7)] = f2bf(p);
          }
        }
      bfrag pa[2], pb[2];
      #pragma unroll
      for (int itl = 0; itl < 2; ++itl){
        int row = itl*16 + cc;
        pa[itl] = *(const bfrag*)(&Pw[row*32 + ((quad ^ (row&3))<<3)]);
      }
      #pragma unroll
      for (int nt = 0; nt < 2; ++nt){
        int row = nt*16 + cc;
        pb[nt] = *(const bfrag*)(&vts[row*64 + (((chunk*4 + quad) ^ (row&7))<<3)]);
      }
      #pragma unroll
      for (int itl = 0; itl < 2; ++itl)
        #pragma unroll
        for (int nt = 0; nt < 2; ++nt)
          yacc[itl][nt] = mfma16(pa[itl], pb[nt], yacc[itl][nt]);
    }
  }
  __syncthreads();                           // b3: all P reads done
  // y (64x256 bf16, token-major, swizzled) into ldsB
  #pragma unroll
  for (int itl = 0; itl < 2; ++itl)
    #pragma unroll
    for (int nt = 0; nt < 2; ++nt)
      #pragma unroll
      for (int r = 0; r < 4; ++r){
        int ii = half*32 + itl*16 + quad*4 + r;
        int col = h*32 + nt*16 + cc;
        ldsB[swx(ii, col>>3)*8 + (col&7)] = f2bf(yacc[itl][nt][r]);
      }
  __syncthreads();                           // b4: y staged

  // ---- phase 3: out = y @ Wp + bp ----
  {
    const int mt = wv & 3;
    const int cb = (wv >> 2)*64;
    f4 o[4];
    #pragma unroll
    for (int nt = 0; nt < 4; ++nt) o[nt] = (f4){0,0,0,0};
    #pragma unroll
    for (int ks = 0; ks < 8; ++ks){
      bfrag ay = *(const bfrag*)(&ldsB[swx(mt*16 + cc, ks*4 + quad)*8]);
      #pragma unroll
      for (int nt = 0; nt < 4; ++nt){
        bfrag bw = *(const bfrag*)(wt + (768 + cb + nt*16 + cc)*256 + ks*32 + quad*8);
        o[nt] = mfma16(ay, bw, o[nt]);
      }
    }
    float* og = out + (size_t)b*(NT*CDIM);
    #pragma unroll
    for (int nt = 0; nt < 4; ++nt){
      int col = cb + nt*16 + cc;
      float bpv = bp[col];
      #pragma unroll
      for (int r = 0; r < 4; ++r){
        int tok = mt*16 + quad*4 + r;
        og[tok*256 + col] = o[nt][r] + bpv;
      }
    }
  }
}

extern "C" void kernel_launch(void* const* d_in, const int* in_sizes, int n_in,
                              void* d_out, int out_size, void* d_ws, size_t ws_size,
                              hipStream_t stream)
{
  const float* x    = (const float*)d_in[0];
  const float* aff  = (const float*)d_in[1];
  const float* Wq   = (const float*)d_in[2];
  const float* bq   = (const float*)d_in[3];
  const float* Wkv  = (const float*)d_in[4];
  const float* bkv  = (const float*)d_in[5];
  const float* Wp   = (const float*)d_in[6];
  const float* bp   = (const float*)d_in[7];
  const float* relt = (const float*)d_in[8];
  const float* egot = (const float*)d_in[9];
  const float* w    = (const float*)d_in[10];
  float* out = (float*)d_out;

  char* ws = (char*)d_ws;
  unsigned short* wt = (unsigned short*)ws;       // 512 KiB bf16 W^T
  float* relb = (float*)(ws + 524288);            // 128 KiB
  float* egob = (float*)(ws + 655360);            //  64 KiB
  float* bqkv = (float*)(ws + 720896);            //   3 KiB

  hipLaunchKernelGGL(prep_kernel, dim3(386), dim3(256), 0, stream,
                     aff, Wq, bq, Wkv, bkv, Wp, relt, egot, wt, relb, egob, bqkv);
  hipLaunchKernelGGL(attn_kernel, dim3(2048), dim3(1024), 0, stream,
                     x, w, bp, out, wt, relb, egob, bqkv);
}